// Round 1
// baseline (233.655 us; speedup 1.0000x reference)
//
#include <hip/hip_runtime.h>
#include <math.h>

// Problem: inp [B=16, S=4096, D=512] fp32, lengths[16] int32.
// out [B, S, D+1]: channels 0..511 copy inp; channel 512 is
// pe[b,s] = cos(s/max(len_b,1)*pi) if s < len_b else 0.
//
// Memory-bound (268.7 MB total traffic, floor ~43 us @ 6.3 TB/s).
//
// Layout trick: output rows are 513 floats (2052 B) so per-row spans are
// misaligned for float4. BUT 4 rows = 2052 dwords = 513 float4s, and each
// 4-row chunk starts at blk*8208 bytes (8208 % 16 == 0) -> every float4
// store in this scheme is 16B-aligned global_store_dwordx4. Loads become
// staggered scalar dwords (wave-contiguous -> still fully coalesced).
//
// Block = 256 threads handles one 4-row chunk (513 float4 stores:
// q = t, t+256, and q=512 done by thread 0). Grid = 65536/4 = 16384 blocks.

#define PB 16
#define PS 4096
#define PD 512
#define PDO 513
#define PI_F 3.14159265358979323846f

__global__ __launch_bounds__(256) void sinpe_kernel(
    const float* __restrict__ inp,
    const int* __restrict__ lengths,
    float* __restrict__ out)
{
    const int blk  = blockIdx.x;       // 0..16383
    const int row0 = blk << 2;         // first of 4 global rows
    const float* __restrict__ in_base = inp + (size_t)row0 * PD;
    float4* __restrict__ out_base = (float4*)(out + (size_t)row0 * PDO);

    const int t = threadIdx.x;

    auto process = [&](int q) {
        const int l0 = q << 2;                       // local dword index 0..2048
        // local row r in 0..3 via compares (no division)
        const int r  = (l0 >= 3 * PDO) ? 3 : (l0 >= 2 * PDO) ? 2 : (l0 >= PDO) ? 1 : 0;
        const int c0 = l0 - r * PDO;                 // channel of first element

        float4 v;
        if (c0 <= PD - 4) {
            // Fast path: all 4 elements are plain copies from row r.
            const float* __restrict__ p = in_base + r * PD + c0;
            v.x = p[0]; v.y = p[1]; v.z = p[2]; v.w = p[3];
        } else {
            // Slow path (~5 lanes per block): span touches the PE channel
            // and/or crosses into the next row.
            float tmp[4];
#pragma unroll
            for (int j = 0; j < 4; ++j) {
                int c  = c0 + j;
                int rr = r;
                if (c >= PDO) { c -= PDO; ++rr; }
                if (c < PD) {
                    tmp[j] = in_base[rr * PD + c];
                } else {                             // c == 512: PE channel
                    const int grow = row0 + rr;
                    const int s    = grow & (PS - 1);
                    const int b    = grow >> 12;
                    const int len  = lengths[b];
                    float pe = 0.0f;
                    if (s < len) {
                        const float fl = fmaxf((float)len, 1.0f);
                        pe = cosf(((float)s / fl) * PI_F);
                    }
                    tmp[j] = pe;
                }
            }
            v.x = tmp[0]; v.y = tmp[1]; v.z = tmp[2]; v.w = tmp[3];
        }
        out_base[q] = v;                             // aligned dwordx4 store
    };

    process(t);
    process(t + 256);
    if (t == 0) process(512);
}

extern "C" void kernel_launch(void* const* d_in, const int* in_sizes, int n_in,
                              void* d_out, int out_size, void* d_ws, size_t ws_size,
                              hipStream_t stream)
{
    const float* inp     = (const float*)d_in[0];
    const int*   lengths = (const int*)d_in[1];
    float*       out     = (float*)d_out;

    const int n_blocks = (PB * PS) / 4;  // 16384 four-row chunks
    sinpe_kernel<<<n_blocks, 256, 0, stream>>>(inp, lengths, out);
}

// Round 2
// 232.795 us; speedup vs baseline: 1.0037x; 1.0037x over previous
//
#include <hip/hip_runtime.h>
#include <math.h>

// Problem: inp [B=16, S=4096, D=512] fp32, lengths[16] int32.
// out [B,S,D+1]: channels 0..511 copy inp; channel 512 is
// pe[b,s] = cos(s/max(len_b,1)*pi) if s < len_b else 0.
//
// Memory-bound: 268.7 MB total, floor ~43 us @ 6.3 TB/s achievable.
//
// Design (m13-copy-shaped): both global streams are ALIGNED dwordx4 with
// 8-deep per-thread ILP; the 512->513 pitch conversion happens in LDS.
//   - block = 256 threads, 16 rows (input 8192 dw, output 8208 dw).
//   - stage: 8 aligned float4 loads/thread -> LDS image (input layout,
//     packed 512 pitch) via lane-contiguous ds_write_b128.
//   - PE values for the 16 rows go to image slots 8192..8207.
//   - emit: 8(+tail) aligned float4 stores/thread; each gathered by 4x
//     ds_read_b32 at idx = l - r (magic-div r = l/513), or 8192+r for the
//     PE channel (branchless cndmask on the address).
//   - LDS dword swizzle phi(idx) = idx ^ ((idx>>5)&3) kills the 8-way
//     bank conflict of the stride-16B gather; on the write side phi only
//     permutes components within each 16B block (branchless XOR swap),
//     so writes remain single ds_write_b128.

#define PB   16
#define PS   4096
#define PD   512
#define PDO  513
#define ROWS 16
#define TPB  256
#define IN_DW  (ROWS * PD)    // 8192
#define IMG_DW (IN_DW + ROWS) // 8208 (image + 16 pe slots)
#define OUT_V4 ((ROWS * PDO) / 4) // 2052
#define PI_F 3.14159265358979323846f

__device__ __forceinline__ int phi(int idx) {
    return idx ^ ((idx >> 5) & 3);
}

__global__ __launch_bounds__(TPB) void sinpe_kernel(
    const float* __restrict__ inp,
    const int* __restrict__ lengths,
    float* __restrict__ out)
{
    __shared__ float lds[IMG_DW];

    const int blk  = blockIdx.x;       // 0..4095
    const int row0 = blk * ROWS;
    const int t    = threadIdx.x;

    const float4* __restrict__ in4  = (const float4*)(inp + (size_t)row0 * PD);
    float4* __restrict__       out4 = (float4*)(out + (size_t)row0 * PDO);

    // ---- issue all global loads first (deep ILP) ----
    float4 v[8];
#pragma unroll
    for (int i = 0; i < 8; ++i)
        v[i] = in4[t + i * TPB];

    // ---- PE channel for the 16 rows (while loads are in flight) ----
    if (t < ROWS) {
        const int grow = row0 + t;
        const int s    = grow & (PS - 1);
        const int b    = grow >> 12;
        const int len  = lengths[b];
        float pe = 0.0f;
        if (s < len) {
            const float fl = fmaxf((float)len, 1.0f);
            pe = cosf(((float)s / fl) * PI_F);
        }
        const int idx = IN_DW + t;
        lds[phi(idx)] = pe;
    }

    // ---- stage to LDS with component-permuted aligned b128 writes ----
    // phi(4k+j) = 4k + (j ^ x), x = (k>>3)&3. x is i-invariant for k=t+256i.
    const int x  = (t >> 3) & 3;
    const bool b0 = (x & 1) != 0;
    const bool b1 = (x & 2) != 0;
#pragma unroll
    for (int i = 0; i < 8; ++i) {
        const int k = t + i * TPB;
        // w[m] = v[m ^ x] via two branchless swap layers
        float a0 = v[i].x, a1 = v[i].y, a2 = v[i].z, a3 = v[i].w;
        float s0 = b0 ? a1 : a0;
        float s1 = b0 ? a0 : a1;
        float s2 = b0 ? a3 : a2;
        float s3 = b0 ? a2 : a3;
        float4 w;
        w.x = b1 ? s2 : s0;
        w.y = b1 ? s3 : s1;
        w.z = b1 ? s0 : s2;
        w.w = b1 ? s1 : s3;
        *(float4*)&lds[4 * k] = w;
    }

    __syncthreads();

    // ---- emit: aligned float4 stores gathered from LDS ----
    auto emit = [&](int q) {
        float tmp[4];
#pragma unroll
        for (int j = 0; j < 4; ++j) {
            const int l = 4 * q + j;                        // out dword 0..8207
            const int r = (int)(((unsigned)l * 8177u) >> 22); // floor(l/513)
            const int c = l - PDO * r;                      // channel 0..512
            const int idx = (c < PD) ? (l - r) : (IN_DW + r);
            tmp[j] = lds[phi(idx)];
        }
        float4 o;
        o.x = tmp[0]; o.y = tmp[1]; o.z = tmp[2]; o.w = tmp[3];
        out4[q] = o;
    };

#pragma unroll
    for (int i = 0; i < 8; ++i)
        emit(t + i * TPB);
    if (t < OUT_V4 - 8 * TPB)   // 2052 - 2048 = 4 tail vectors
        emit(t + 8 * TPB);
}

extern "C" void kernel_launch(void* const* d_in, const int* in_sizes, int n_in,
                              void* d_out, int out_size, void* d_ws, size_t ws_size,
                              hipStream_t stream)
{
    const float* inp     = (const float*)d_in[0];
    const int*   lengths = (const int*)d_in[1];
    float*       out     = (float*)d_out;

    const int n_blocks = (PB * PS) / ROWS;  // 4096
    sinpe_kernel<<<n_blocks, TPB, 0, stream>>>(inp, lengths, out);
}

// Round 3
// 231.958 us; speedup vs baseline: 1.0073x; 1.0036x over previous
//
#include <hip/hip_runtime.h>
#include <math.h>

// Problem: inp [B=16, S=4096, D=512] fp32, lengths[16] int32.
// out [B,S,D+1]: channels 0..511 copy inp; channel 512 is
// pe[b,s] = cos(s/max(len_b,1)*pi) if s < len_b else 0.
//
// Memory-bound: ~268.7 MB total, floor ~43 us @ 6.3 TB/s achievable.
//
// v3: register funnel, no LDS, no barrier, both streams aligned dwordx4.
// Output chunk q (dwords 4q..4q+3) sources input dwords 4q-r..4q+3-r
// (r = row = floor(4q/513)). Those live in the two ALIGNED input chunks
// prev = in4[q-(r>>2)-1], cur = in4[q-(r>>2)]; combine with a funnel
// shift by delta = r&3 (9 cndmask, branchless). prev is the line right
// before cur -> L1/L2 hit, no extra HBM traffic.
//
// PE dword (c==512) provably sits at component delta of its chunk
// (c0 = 4q-513r == -r mod 4), and components after it (next row) are
// exactly clean[m-1]. Dirty chunks (c0>=509, ~8 lanes per block) take a
// rare branch: w[m] = m<delta ? clean[m] : m==delta ? pe : clean[m-1].

#define PS   4096
#define PD   512
#define PDO  513
#define PI_F 3.14159265358979323846f
#define OUT_V4 8404992   // 16*4096*513/4
#define IN_V4  8388608   // 16*4096*512/4
#define TPB  256
#define CPT  4           // chunks per thread

__global__ __launch_bounds__(TPB) void sinpe_kernel(
    const float* __restrict__ inp,
    const int* __restrict__ lengths,
    float* __restrict__ out)
{
    const float4* __restrict__ in4  = (const float4*)inp;
    float4* __restrict__       out4 = (float4*)out;

    const int q0 = blockIdx.x * (TPB * CPT) + threadIdx.x;

    float4 cur[CPT], prv[CPT];
    int r_[CPT], c0_[CPT];

    // ---- issue all 8 global loads first (deep ILP) ----
#pragma unroll
    for (int k = 0; k < CPT; ++k) {
        const int q  = q0 + k * TPB;
        const int l0 = q << 2;                                   // out dword
        const int r  = (int)__umulhi((unsigned)l0, 8372256u);    // l0/513
        const int c0 = l0 - r * PDO;                             // 0..512
        const int sh = r >> 2;
        const int si = q - sh;
        int ci = si;     if (ci > IN_V4 - 1) ci = IN_V4 - 1;     // last chunk: cur unused
        int pi = si - 1; if (pi < 0)         pi = 0;             // q=0: prev unused
        cur[k] = in4[ci];
        prv[k] = in4[pi];
        r_[k] = r; c0_[k] = c0;
    }

    // ---- funnel + store ----
#pragma unroll
    for (int k = 0; k < CPT; ++k) {
        const int q   = q0 + k * TPB;
        const int r   = r_[k];
        const int c0  = c0_[k];
        const int dlt = r & 3;

        // X[-4..-1] = prv, X[0..3] = cur; clean out[m] = X[m-dlt]
        const float px = prv[k].x, py = prv[k].y, pz = prv[k].z, pw = prv[k].w;
        const float cx = cur[k].x, cy = cur[k].y, cz = cur[k].z, cw = cur[k].w;
        const bool d2 = (dlt & 2) != 0;
        const bool d1 = (dlt & 1) != 0;
        // A[j] = d2 ? X[j-2] : X[j]
        const float Am1 = d2 ? py : pw;
        const float A0  = d2 ? pz : cx;
        const float A1  = d2 ? pw : cy;
        const float A2  = d2 ? cx : cz;
        const float A3  = d2 ? cy : cw;
        // out[m] = d1 ? A[m-1] : A[m]
        float w0 = d1 ? Am1 : A0;
        float w1 = d1 ? A0  : A1;
        float w2 = d1 ? A1  : A2;
        float w3 = d1 ? A2  : A3;

        if (c0 >= 509) {
            // dirty: chunk contains the PE dword (c==512) at component
            // mpe = 512-c0 == dlt; later components belong to row r+1.
            const int mpe = 512 - c0;
            const int b   = r >> 12;
            const int s   = r & (PS - 1);
            const int len = lengths[b];
            float pe = 0.0f;
            if (s < len)
                pe = cosf(((float)s / fmaxf((float)len, 1.0f)) * PI_F);
            const float n0 = (mpe == 0) ? pe : w0;
            const float n1 = (mpe == 1) ? pe : ((mpe < 1) ? w0 : w1);
            const float n2 = (mpe == 2) ? pe : ((mpe < 2) ? w1 : w2);
            const float n3 = (mpe == 3) ? pe : w2;   // mpe<3 -> clean[2]
            w0 = n0; w1 = n1; w2 = n2; w3 = n3;
        }

        float4 o;
        o.x = w0; o.y = w1; o.z = w2; o.w = w3;
        out4[q] = o;                                  // aligned dwordx4
    }
}

extern "C" void kernel_launch(void* const* d_in, const int* in_sizes, int n_in,
                              void* d_out, int out_size, void* d_ws, size_t ws_size,
                              hipStream_t stream)
{
    const float* inp     = (const float*)d_in[0];
    const int*   lengths = (const int*)d_in[1];
    float*       out     = (float*)d_out;

    const int n_blocks = OUT_V4 / (TPB * CPT);  // 8208, exact (no tail)
    sinpe_kernel<<<n_blocks, TPB, 0, stream>>>(inp, lengths, out);
}